// Round 3
// baseline (4102.871 us; speedup 1.0000x reference)
//
#include <hip/hip_runtime.h>
#include <hip/hip_fp16.h>
#include <stdint.h>

// Problem constants
#define B_     16
#define T_     1000
#define F_     512
#define H_     512
#define NG_    1024     // 2H
#define M1_    16000    // B*T
#define STEPS_ 2000     // 2T

// ws layout (bytes)
#define WX_OFF     0            // __half[16000*1024] BN'd gates (wz | wh)      32,768,000 B
#define OUTPRE_OFF 32768000     // __half[16000*1024] hidden concat (pre-LN)    32,768,000 B
#define HTAG_OFF   65536000     // uint64_t[16 chains][2 parity][512]              131,072 B

__device__ __forceinline__ int swz(int c) { return c + ((c >> 5) & 3) * 4; }  // LDS bank swizzle

typedef _Float16 h2_t __attribute__((ext_vector_type(2)));
union U32H2 { uint32_t u; h2_t h; };

__device__ __forceinline__ float dot2f(uint32_t a, uint32_t b, float c) {
#if __has_builtin(__builtin_amdgcn_fdot2)
    U32H2 ua, ub; ua.u = a; ub.u = b;
    return __builtin_amdgcn_fdot2(ua.h, ub.h, c, false);
#else
    __half2 ha = *(__half2*)&a, hb = *(__half2*)&b;
    float2 fa = __half22float2(ha), fb = __half22float2(hb);
    return fmaf(fa.x, fb.x, fmaf(fa.y, fb.y, c));
#endif
}

// ---------------------------------------------------------------------------
// init: reset tagged h buffers (h0 = 0, tag 0; parity-1 = sentinel), copy x_len
// ---------------------------------------------------------------------------
__global__ void init_kernel(uint64_t* __restrict__ htag, const int* __restrict__ xlen,
                            float* __restrict__ out_tail) {
    int i = blockIdx.x * 256 + threadIdx.x;
    if (i < B_ * 2 * H_) {
        uint64_t v = ((i >> 9) & 1) ? 0xFFFFFFFF00000000ULL : 0ULL; // parity1 sentinel / tag0+0.0f
        __hip_atomic_store(&htag[i], v, __ATOMIC_RELAXED, __HIP_MEMORY_SCOPE_AGENT);
    }
    if (i < B_) out_tail[i] = (float)xlen[i];
}

// ---------------------------------------------------------------------------
// Phase 1: WX[b,t,n] = BN(x[b,t,:] . W[n,:] + bias[n]),  n<512: Wz/z, else Wh/h
// ---------------------------------------------------------------------------
__global__ __launch_bounds__(256) void gemm_gates(
    const float* __restrict__ x, const float* __restrict__ Wz, const float* __restrict__ Wh,
    const float* __restrict__ bz, const float* __restrict__ bh,
    const float* __restrict__ zg, const float* __restrict__ zb, const float* __restrict__ zm, const float* __restrict__ zv,
    const float* __restrict__ hg, const float* __restrict__ hb, const float* __restrict__ hm, const float* __restrict__ hv,
    __half* __restrict__ WX)
{
    __shared__ float As[16][132];
    __shared__ float Bs[16][144];
    int tid = threadIdx.x;
    int bm = blockIdx.x >> 3, bn = blockIdx.x & 7;
    int m0 = bm * 128, n0 = bn * 128;
    bool isZ = (n0 < 512);
    const float* Wsrc = isZ ? Wz : Wh;
    int nc0 = isZ ? n0 : (n0 - 512);
    const float* biasp = isZ ? bz : bh;
    const float* gp = isZ ? zg : hg;  const float* bp = isZ ? zb : hb;
    const float* mp = isZ ? zm : hm;  const float* vp = isZ ? zv : hv;
    int tm = tid >> 4, tn = tid & 15;
    float acc[8][8] = {};

    for (int k0 = 0; k0 < 512; k0 += 16) {
#pragma unroll
        for (int i = 0; i < 2; ++i) {
            int f = tid * 2 + i;
            int row = f >> 2, c4 = (f & 3) * 4;
            float4 v = *(const float4*)(x + (size_t)(m0 + row) * 512 + k0 + c4);
            As[c4 + 0][row] = v.x; As[c4 + 1][row] = v.y;
            As[c4 + 2][row] = v.z; As[c4 + 3][row] = v.w;
        }
#pragma unroll
        for (int i = 0; i < 2; ++i) {
            int f = tid * 2 + i;
            int row = f >> 2, c4 = (f & 3) * 4;
            float4 v = *(const float4*)(Wsrc + (size_t)(nc0 + row) * 512 + k0 + c4);
            int r = swz(row);
            Bs[c4 + 0][r] = v.x; Bs[c4 + 1][r] = v.y;
            Bs[c4 + 2][r] = v.z; Bs[c4 + 3][r] = v.w;
        }
        __syncthreads();
#pragma unroll
        for (int kk = 0; kk < 16; ++kk) {
            float a[8], b[8];
            *(float4*)&a[0] = *(const float4*)&As[kk][tm * 8];
            *(float4*)&a[4] = *(const float4*)&As[kk][tm * 8 + 4];
            *(float4*)&b[0] = *(const float4*)&Bs[kk][swz(tn * 8)];
            *(float4*)&b[4] = *(const float4*)&Bs[kk][swz(tn * 8) + 4];
#pragma unroll
            for (int i = 0; i < 8; ++i)
#pragma unroll
                for (int j = 0; j < 8; ++j)
                    acc[i][j] = fmaf(a[i], b[j], acc[i][j]);
        }
        __syncthreads();
    }

    float sc[8], sh[8];
#pragma unroll
    for (int j = 0; j < 8; ++j) {
        int nc = nc0 + tn * 8 + j;
        float s = gp[nc] * rsqrtf(vp[nc] + 1e-5f);
        sc[j] = s;
        sh[j] = (biasp[nc] - mp[nc]) * s + bp[nc];
    }
#pragma unroll
    for (int i = 0; i < 8; ++i) {
        size_t rowoff = (size_t)(m0 + tm * 8 + i) * NG_ + n0 + tn * 8;
#pragma unroll
        for (int j = 0; j < 4; ++j) {
            float v0 = acc[i][2 * j] * sc[2 * j] + sh[2 * j];
            float v1 = acc[i][2 * j + 1] * sc[2 * j + 1] + sh[2 * j + 1];
            *(__half2*)(WX + rowoff + 2 * j) = __floats2half2_rn(v0, v1);
        }
    }
}

// ---------------------------------------------------------------------------
// Phase 2: LiGRU recurrence. 16 chains x 16 WGs; WG g of chain c owns cols
// [32g,32g+32). Thread (rg,ck), rg=tid>>4, ck=tid&15: holds 4 U-rows
// {z:2rg, z:2rg+1, h:2rg, h:2rg+1} x K-chunk [32ck,32ck+32) as fp16x2 regs.
// Per step: poll 2 tagged u64 -> stage fp16 h in LDS -> 4x ds_read_b128 ->
// 64 dot2 -> 16-lane shfl reduce -> lane ck==0 computes gates for cols
// j0=32g+2rg, j0+1 and publishes IMMEDIATELY (no second barrier on path).
// hold-state + 1-step-prefetched WX live in the gate lane's registers.
// ---------------------------------------------------------------------------
__global__ __launch_bounds__(256, 1) void recur_kernel(
    const __half* __restrict__ WX, const float* __restrict__ U,
    uint64_t* __restrict__ htag, __half* __restrict__ out_pre)
{
    int bI = blockIdx.x;
    int X  = bI & 7;          // target XCD (round-robin dispatch heuristic)
    int s  = bI >> 3;
    int c  = X * 2 + (s & 1); // chain
    int g  = s >> 1;          // column-group 0..15
    int tid = threadIdx.x;
    int rg = tid >> 4;        // row-group 0..15 (2 z-rows + 2 h-rows)
    int ck = tid & 15;        // 32-wide K chunk

    // Load 4 U rows x 32-half chunk into fp16x2 registers
    uint32_t ureg[4][16];
    {
        int rows[4];
        rows[0] = g * 32 + 2 * rg;           // z row for col j0
        rows[1] = rows[0] + 1;               // z row for col j0+1
        rows[2] = H_ + g * 32 + 2 * rg;      // h row for col j0
        rows[3] = rows[2] + 1;               // h row for col j0+1
#pragma unroll
        for (int r = 0; r < 4; ++r) {
            const float4* up = (const float4*)(U + (size_t)rows[r] * H_ + ck * 32);
#pragma unroll
            for (int q = 0; q < 8; ++q) {
                float4 v = up[q];
                __half2 a = __floats2half2_rn(v.x, v.y);
                __half2 b = __floats2half2_rn(v.z, v.w);
                ureg[r][2 * q]     = *(uint32_t*)&a;
                ureg[r][2 * q + 1] = *(uint32_t*)&b;
            }
        }
    }

    // LDS: h fp16, chunk ck at half-offset ck*40 (80B stride: 16B-aligned,
    // bank offsets 20ck%32 -> max 2 distinct addrs/bank with 4-lane broadcast = free)
    __shared__ __align__(16) __half h_s[16 * 40];

    uint64_t* myb = htag + (size_t)c * 1024;   // [2][512]
    int p0 = tid * 2, p1 = tid * 2 + 1;

    bool gate = (ck == 0);
    int j0 = g * 32 + 2 * rg;                  // this gate lane's columns j0, j0+1
    float hold0 = 0.f, hold1 = 0.f;            // fp32 recurrent state (register-resident)
    __half2 wz2, wh2;                          // prefetched WX for current step
    if (gate) {
        const __half* wrow = WX + (size_t)(c * T_ + 0) * NG_;   // t=0 -> forward, batch c
        wz2 = *(const __half2*)(wrow + j0);
        wh2 = *(const __half2*)(wrow + H_ + j0);
    }

    for (int t = 0; t < STEPS_; ++t) {
        // ---- poll h_t (tag == t), busy spin ----
        uint64_t* buf = myb + (size_t)(t & 1) * 512;
        uint32_t tag = (uint32_t)t;
        uint64_t v0 = __hip_atomic_load(&buf[p0], __ATOMIC_RELAXED, __HIP_MEMORY_SCOPE_AGENT);
        uint64_t v1 = __hip_atomic_load(&buf[p1], __ATOMIC_RELAXED, __HIP_MEMORY_SCOPE_AGENT);
        while ((uint32_t)(v0 >> 32) != tag || (uint32_t)(v1 >> 32) != tag) {
            if ((uint32_t)(v0 >> 32) != tag)
                v0 = __hip_atomic_load(&buf[p0], __ATOMIC_RELAXED, __HIP_MEMORY_SCOPE_AGENT);
            if ((uint32_t)(v1 >> 32) != tag)
                v1 = __hip_atomic_load(&buf[p1], __ATOMIC_RELAXED, __HIP_MEMORY_SCOPE_AGENT);
        }
        {   // stage fp16 pair (chunk = tid>>4, loc = (2*tid)&31; same chunk, 4B-aligned)
            __half2 hh = __floats2half2_rn(__uint_as_float((uint32_t)v0),
                                           __uint_as_float((uint32_t)v1));
            *(__half2*)(h_s + (p0 >> 5) * 40 + (p0 & 31)) = hh;
        }
        __syncthreads();   // sync1: h_s(t) complete

        // ---- 4-row x 32-chunk dot (reads 64B of h, reuses x4) ----
        float a0 = 0.f, a1 = 0.f, a2 = 0.f, a3 = 0.f;
        const uint4* h4 = (const uint4*)(h_s + ck * 40);
#pragma unroll
        for (int q = 0; q < 4; ++q) {
            uint4 hv = h4[q];
            a0 = dot2f(ureg[0][4 * q + 0], hv.x, a0);
            a0 = dot2f(ureg[0][4 * q + 1], hv.y, a0);
            a0 = dot2f(ureg[0][4 * q + 2], hv.z, a0);
            a0 = dot2f(ureg[0][4 * q + 3], hv.w, a0);
            a1 = dot2f(ureg[1][4 * q + 0], hv.x, a1);
            a1 = dot2f(ureg[1][4 * q + 1], hv.y, a1);
            a1 = dot2f(ureg[1][4 * q + 2], hv.z, a1);
            a1 = dot2f(ureg[1][4 * q + 3], hv.w, a1);
            a2 = dot2f(ureg[2][4 * q + 0], hv.x, a2);
            a2 = dot2f(ureg[2][4 * q + 1], hv.y, a2);
            a2 = dot2f(ureg[2][4 * q + 2], hv.z, a2);
            a2 = dot2f(ureg[2][4 * q + 3], hv.w, a2);
            a3 = dot2f(ureg[3][4 * q + 0], hv.x, a3);
            a3 = dot2f(ureg[3][4 * q + 1], hv.y, a3);
            a3 = dot2f(ureg[3][4 * q + 2], hv.z, a3);
            a3 = dot2f(ureg[3][4 * q + 3], hv.w, a3);
        }
        // ---- reduce across the 16 ck lanes (within-wave, groups of 16) ----
#pragma unroll
        for (int m = 1; m < 16; m <<= 1) {
            a0 += __shfl_xor(a0, m);
            a1 += __shfl_xor(a1, m);
            a2 += __shfl_xor(a2, m);
            a3 += __shfl_xor(a3, m);
        }

        // ---- gate lanes: compute + publish immediately ----
        if (gate) {
            float2 wz = __half22float2(wz2), wh = __half22float2(wh2);
            float z0 = 1.f / (1.f + __expf(-(wz.x + a0)));
            float z1 = 1.f / (1.f + __expf(-(wz.y + a1)));
            float hc0 = fmaxf(wh.x + a2, 0.f);
            float hc1 = fmaxf(wh.y + a3, 0.f);
            float hn0 = z0 * hold0 + (1.f - z0) * hc0;
            float hn1 = z1 * hold1 + (1.f - z1) * hc1;
            hold0 = hn0; hold1 = hn1;
            uint64_t* nb = myb + (size_t)((t + 1) & 1) * 512;
            uint64_t tagup = (uint64_t)(uint32_t)(t + 1) << 32;
            __hip_atomic_store(&nb[j0], tagup | (uint64_t)__float_as_uint(hn0),
                               __ATOMIC_RELAXED, __HIP_MEMORY_SCOPE_AGENT);
            __hip_atomic_store(&nb[j0 + 1], tagup | (uint64_t)__float_as_uint(hn1),
                               __ATOMIC_RELAXED, __HIP_MEMORY_SCOPE_AGENT);
            // out_pre store (off critical path)
            size_t off;
            if (t < T_) off = ((size_t)(c * T_ + t)) * NG_ + j0;
            else        off = ((size_t)((B_ - 1 - c) * T_ + (t - T_))) * NG_ + H_ + j0;
            *(__half2*)(out_pre + off) = __floats2half2_rn(hn0, hn1);
            // prefetch WX for step t+1 (latency hides behind next poll)
            int tn2 = (t + 1 < STEPS_) ? (t + 1) : t;
            int sb = (tn2 < T_) ? c : (B_ - 1 - c);
            int st = (tn2 < T_) ? tn2 : (tn2 - T_);
            const __half* wrow = WX + (size_t)(sb * T_ + st) * NG_;
            wz2 = *(const __half2*)(wrow + j0);
            wh2 = *(const __half2*)(wrow + H_ + j0);
        }
        __syncthreads();   // sync2: all h_s(t) reads done -> safe to stage t+1
    }
}

// ---------------------------------------------------------------------------
// Phase 3a: LayerNorm over last dim (1024), in place on f16 buffer
// ---------------------------------------------------------------------------
__global__ __launch_bounds__(256) void ln_kernel(__half* __restrict__ buf,
                                                 const float* __restrict__ g,
                                                 const float* __restrict__ b) {
    __shared__ float red[2][4];
    int row = blockIdx.x, tid = threadIdx.x;
    __half* p = buf + (size_t)row * NG_ + tid * 4;
    uint2 raw = *(const uint2*)p;
    __half2 h01 = *(__half2*)&raw.x, h23 = *(__half2*)&raw.y;
    float2 f01 = __half22float2(h01), f23 = __half22float2(h23);
    float s = f01.x + f01.y + f23.x + f23.y;
    float ss = fmaf(f01.x, f01.x, fmaf(f01.y, f01.y, fmaf(f23.x, f23.x, f23.y * f23.y)));
#pragma unroll
    for (int m = 32; m >= 1; m >>= 1) { s += __shfl_xor(s, m); ss += __shfl_xor(ss, m); }
    int w = tid >> 6;
    if ((tid & 63) == 0) { red[0][w] = s; red[1][w] = ss; }
    __syncthreads();
    float S = red[0][0] + red[0][1] + red[0][2] + red[0][3];
    float SS = red[1][0] + red[1][1] + red[1][2] + red[1][3];
    float mu = S * (1.f / NG_);
    float var = SS * (1.f / NG_) - mu * mu;
    float rstd = rsqrtf(var + 1e-5f);
    int d = tid * 4;
    float o0 = (f01.x - mu) * rstd * g[d + 0] + b[d + 0];
    float o1 = (f01.y - mu) * rstd * g[d + 1] + b[d + 1];
    float o2 = (f23.x - mu) * rstd * g[d + 2] + b[d + 2];
    float o3 = (f23.y - mu) * rstd * g[d + 3] + b[d + 3];
    __half2 a = __floats2half2_rn(o0, o1), c = __floats2half2_rn(o2, o3);
    uint2 out; out.x = *(uint32_t*)&a; out.y = *(uint32_t*)&c;
    *(uint2*)p = out;
}

// ---------------------------------------------------------------------------
// Phase 3b: projection GEMM: out[m,e] = tanh(LN[m,:] . pjW[e,:] + pjb[e]), fp32 out
// ---------------------------------------------------------------------------
__global__ __launch_bounds__(256) void gemm_proj(
    const __half* __restrict__ Ain, const float* __restrict__ pjW,
    const float* __restrict__ pjb, float* __restrict__ outp)
{
    __shared__ float As[16][132];
    __shared__ float Bs[16][144];
    int tid = threadIdx.x;
    int bm = blockIdx.x >> 3, bn = blockIdx.x & 7;
    int m0 = bm * 128, n0 = bn * 128;
    int tm = tid >> 4, tn = tid & 15;
    float acc[8][8] = {};

    for (int k0 = 0; k0 < 1024; k0 += 16) {
        {
            int row = tid >> 1, hb = (tid & 1) * 8;
            uint4 raw = *(const uint4*)(Ain + (size_t)(m0 + row) * NG_ + k0 + hb);
            const __half2* hp = (const __half2*)&raw;
#pragma unroll
            for (int q = 0; q < 4; ++q) {
                float2 f = __half22float2(hp[q]);
                As[hb + 2 * q][row] = f.x;
                As[hb + 2 * q + 1][row] = f.y;
            }
        }
#pragma unroll
        for (int i = 0; i < 2; ++i) {
            int f = tid * 2 + i;
            int row = f >> 2, c4 = (f & 3) * 4;
            float4 v = *(const float4*)(pjW + (size_t)(n0 + row) * 1024 + k0 + c4);
            int r = swz(row);
            Bs[c4 + 0][r] = v.x; Bs[c4 + 1][r] = v.y;
            Bs[c4 + 2][r] = v.z; Bs[c4 + 3][r] = v.w;
        }
        __syncthreads();
#pragma unroll
        for (int kk = 0; kk < 16; ++kk) {
            float a[8], b[8];
            *(float4*)&a[0] = *(const float4*)&As[kk][tm * 8];
            *(float4*)&a[4] = *(const float4*)&As[kk][tm * 8 + 4];
            *(float4*)&b[0] = *(const float4*)&Bs[kk][swz(tn * 8)];
            *(float4*)&b[4] = *(const float4*)&Bs[kk][swz(tn * 8) + 4];
#pragma unroll
            for (int i = 0; i < 8; ++i)
#pragma unroll
                for (int j = 0; j < 8; ++j)
                    acc[i][j] = fmaf(a[i], b[j], acc[i][j]);
        }
        __syncthreads();
    }

#pragma unroll
    for (int i = 0; i < 8; ++i) {
        size_t rowoff = (size_t)(m0 + tm * 8 + i) * NG_ + n0 + tn * 8;
#pragma unroll
        for (int j = 0; j < 8; ++j) {
            int n = n0 + tn * 8 + j;
            outp[rowoff + j] = tanhf(acc[i][j] + pjb[n]);
        }
    }
}

// ---------------------------------------------------------------------------
extern "C" void kernel_launch(void* const* d_in, const int* in_sizes, int n_in,
                              void* d_out, int out_size, void* d_ws, size_t ws_size,
                              hipStream_t stream) {
    const float* x    = (const float*)d_in[0];
    const int*   xlen = (const int*)  d_in[1];
    const float* Wz   = (const float*)d_in[2];
    const float* bz   = (const float*)d_in[3];
    const float* Wh   = (const float*)d_in[4];
    const float* bh   = (const float*)d_in[5];
    const float* U    = (const float*)d_in[6];
    const float* zg   = (const float*)d_in[7];
    const float* zb   = (const float*)d_in[8];
    const float* zm   = (const float*)d_in[9];
    const float* zv   = (const float*)d_in[10];
    const float* hg   = (const float*)d_in[11];
    const float* hb   = (const float*)d_in[12];
    const float* hm   = (const float*)d_in[13];
    const float* hv   = (const float*)d_in[14];
    const float* lng  = (const float*)d_in[15];
    const float* lnb  = (const float*)d_in[16];
    const float* pjW  = (const float*)d_in[17];
    const float* pjb  = (const float*)d_in[18];

    char* ws = (char*)d_ws;
    __half*   WX      = (__half*)(ws + WX_OFF);
    __half*   out_pre = (__half*)(ws + OUTPRE_OFF);
    uint64_t* htag    = (uint64_t*)(ws + HTAG_OFF);
    float* out = (float*)d_out;

    init_kernel<<<64, 256, 0, stream>>>(htag, xlen, out + (size_t)M1_ * NG_);
    gemm_gates<<<1000, 256, 0, stream>>>(x, Wz, Wh, bz, bh, zg, zb, zm, zv,
                                         hg, hb, hm, hv, WX);
    recur_kernel<<<256, 256, 0, stream>>>(WX, U, htag, out_pre);
    ln_kernel<<<M1_, 256, 0, stream>>>(out_pre, lng, lnb);
    gemm_proj<<<1000, 256, 0, stream>>>(out_pre, pjW, pjb, out);
}

// Round 4
// 3865.194 us; speedup vs baseline: 1.0615x; 1.0615x over previous
//
#include <hip/hip_runtime.h>
#include <hip/hip_fp16.h>
#include <stdint.h>

// Problem constants
#define B_     16
#define T_     1000
#define F_     512
#define H_     512
#define NG_    1024     // 2H
#define M1_    16000    // B*T
#define STEPS_ 2000     // 2T

// ws layout (bytes)
#define WX_OFF     0            // __half[16000*1024] BN'd gates (wz | wh)      32,768,000 B
#define OUTPRE_OFF 32768000     // __half[16000*1024] hidden concat (pre-LN)    32,768,000 B
#define HTAG_OFF   65536000     // uint64_t[16 chains][2 parity][512]              131,072 B

__device__ __forceinline__ int swz(int c) { return c + ((c >> 5) & 3) * 4; }  // LDS bank swizzle

typedef _Float16 h2_t __attribute__((ext_vector_type(2)));
union U32H2 { uint32_t u; h2_t h; };

__device__ __forceinline__ float dot2f(uint32_t a, uint32_t b, float c) {
#if __has_builtin(__builtin_amdgcn_fdot2)
    U32H2 ua, ub; ua.u = a; ub.u = b;
    return __builtin_amdgcn_fdot2(ua.h, ub.h, c, false);
#else
    __half2 ha = *(__half2*)&a, hb = *(__half2*)&b;
    float2 fa = __half22float2(ha), fb = __half22float2(hb);
    return fmaf(fa.x, fb.x, fmaf(fa.y, fb.y, c));
#endif
}

// ---------------------------------------------------------------------------
// init: reset tagged h buffers (h0 = 0, tag 0; parity-1 = sentinel), copy x_len
// ---------------------------------------------------------------------------
__global__ void init_kernel(uint64_t* __restrict__ htag, const int* __restrict__ xlen,
                            float* __restrict__ out_tail) {
    int i = blockIdx.x * 256 + threadIdx.x;
    if (i < B_ * 2 * H_) {
        uint64_t v = ((i >> 9) & 1) ? 0xFFFFFFFF00000000ULL : 0ULL; // parity1 sentinel / tag0+0.0f
        __hip_atomic_store(&htag[i], v, __ATOMIC_RELAXED, __HIP_MEMORY_SCOPE_AGENT);
    }
    if (i < B_) out_tail[i] = (float)xlen[i];
}

// ---------------------------------------------------------------------------
// Phase 1: WX[b,t,n] = BN(x[b,t,:] . W[n,:] + bias[n]),  n<512: Wz/z, else Wh/h
// ---------------------------------------------------------------------------
__global__ __launch_bounds__(256) void gemm_gates(
    const float* __restrict__ x, const float* __restrict__ Wz, const float* __restrict__ Wh,
    const float* __restrict__ bz, const float* __restrict__ bh,
    const float* __restrict__ zg, const float* __restrict__ zb, const float* __restrict__ zm, const float* __restrict__ zv,
    const float* __restrict__ hg, const float* __restrict__ hb, const float* __restrict__ hm, const float* __restrict__ hv,
    __half* __restrict__ WX)
{
    __shared__ float As[16][132];
    __shared__ float Bs[16][144];
    int tid = threadIdx.x;
    int bm = blockIdx.x >> 3, bn = blockIdx.x & 7;
    int m0 = bm * 128, n0 = bn * 128;
    bool isZ = (n0 < 512);
    const float* Wsrc = isZ ? Wz : Wh;
    int nc0 = isZ ? n0 : (n0 - 512);
    const float* biasp = isZ ? bz : bh;
    const float* gp = isZ ? zg : hg;  const float* bp = isZ ? zb : hb;
    const float* mp = isZ ? zm : hm;  const float* vp = isZ ? zv : hv;
    int tm = tid >> 4, tn = tid & 15;
    float acc[8][8] = {};

    for (int k0 = 0; k0 < 512; k0 += 16) {
#pragma unroll
        for (int i = 0; i < 2; ++i) {
            int f = tid * 2 + i;
            int row = f >> 2, c4 = (f & 3) * 4;
            float4 v = *(const float4*)(x + (size_t)(m0 + row) * 512 + k0 + c4);
            As[c4 + 0][row] = v.x; As[c4 + 1][row] = v.y;
            As[c4 + 2][row] = v.z; As[c4 + 3][row] = v.w;
        }
#pragma unroll
        for (int i = 0; i < 2; ++i) {
            int f = tid * 2 + i;
            int row = f >> 2, c4 = (f & 3) * 4;
            float4 v = *(const float4*)(Wsrc + (size_t)(nc0 + row) * 512 + k0 + c4);
            int r = swz(row);
            Bs[c4 + 0][r] = v.x; Bs[c4 + 1][r] = v.y;
            Bs[c4 + 2][r] = v.z; Bs[c4 + 3][r] = v.w;
        }
        __syncthreads();
#pragma unroll
        for (int kk = 0; kk < 16; ++kk) {
            float a[8], b[8];
            *(float4*)&a[0] = *(const float4*)&As[kk][tm * 8];
            *(float4*)&a[4] = *(const float4*)&As[kk][tm * 8 + 4];
            *(float4*)&b[0] = *(const float4*)&Bs[kk][swz(tn * 8)];
            *(float4*)&b[4] = *(const float4*)&Bs[kk][swz(tn * 8) + 4];
#pragma unroll
            for (int i = 0; i < 8; ++i)
#pragma unroll
                for (int j = 0; j < 8; ++j)
                    acc[i][j] = fmaf(a[i], b[j], acc[i][j]);
        }
        __syncthreads();
    }

    float sc[8], sh[8];
#pragma unroll
    for (int j = 0; j < 8; ++j) {
        int nc = nc0 + tn * 8 + j;
        float s = gp[nc] * rsqrtf(vp[nc] + 1e-5f);
        sc[j] = s;
        sh[j] = (biasp[nc] - mp[nc]) * s + bp[nc];
    }
#pragma unroll
    for (int i = 0; i < 8; ++i) {
        size_t rowoff = (size_t)(m0 + tm * 8 + i) * NG_ + n0 + tn * 8;
#pragma unroll
        for (int j = 0; j < 4; ++j) {
            float v0 = acc[i][2 * j] * sc[2 * j] + sh[2 * j];
            float v1 = acc[i][2 * j + 1] * sc[2 * j + 1] + sh[2 * j + 1];
            *(__half2*)(WX + rowoff + 2 * j) = __floats2half2_rn(v0, v1);
        }
    }
}

// ---------------------------------------------------------------------------
// Phase 2: LiGRU recurrence. 16 chains x 8 WGs x 512 threads; WG g of chain c
// owns cols [64g, 64g+64). Thread (rg,ck), rg=tid>>4 (0..31), ck=tid&15:
// 4 U-rows {z:2rg, z:2rg+1, h:2rg, h:2rg+1} x K-chunk [32ck,32ck+32) in regs.
// ONLY WAVE 0 POLLS: lane l polls tagged u64s {l+64k, k=0..7} (coalesced),
// reloading only stale entries; on detect it holds all 512 h values and
// stages them to LDS as fp16. Tag+payload in one atom = single MALL hop;
// poll-success == read-complete, so parity double-buffer is race-free
// (publish(t+2) happens-after observe-all(t+1) happens-after publish(t+1)
// happens-after observe-all(t)).
// ---------------------------------------------------------------------------
__global__ __launch_bounds__(512, 1) void recur_kernel(
    const __half* __restrict__ WX, const float* __restrict__ U,
    uint64_t* __restrict__ htag, __half* __restrict__ out_pre)
{
    int bI = blockIdx.x;
    int X  = bI & 7;           // XCD residue (perf heuristic only)
    int s  = bI >> 3;          // 0..15
    int c  = X + 8 * (s & 1);  // chain
    int g  = s >> 1;           // column-group 0..7 (64 cols)
    int tid = threadIdx.x;
    int rg = tid >> 4;         // row-group 0..31 (2 z-rows + 2 h-rows)
    int ck = tid & 15;         // 32-wide K chunk

    // Load 4 U rows x 32-half chunk into fp16x2 registers (64 VGPRs)
    uint32_t ureg[4][16];
    {
        int base = g * 64 + 2 * rg;
        int rows[4] = { base, base + 1, H_ + base, H_ + base + 1 };
#pragma unroll
        for (int r = 0; r < 4; ++r) {
            const float4* up = (const float4*)(U + (size_t)rows[r] * H_ + ck * 32);
#pragma unroll
            for (int q = 0; q < 8; ++q) {
                float4 v = up[q];
                __half2 a = __floats2half2_rn(v.x, v.y);
                __half2 b = __floats2half2_rn(v.z, v.w);
                ureg[r][2 * q]     = *(uint32_t*)&a;
                ureg[r][2 * q + 1] = *(uint32_t*)&b;
            }
        }
    }

    // h fp16 in LDS: col -> chunk (col>>5) at half-offset chunk*40 + (col&31)
    __shared__ __align__(16) __half h_s[16 * 40];

    uint64_t* myb = htag + (size_t)c * 1024;   // [2][512]

    bool gate = (ck == 0);
    int j0 = g * 64 + 2 * rg;                  // gate lane's columns j0, j0+1
    float hold0 = 0.f, hold1 = 0.f;            // fp32 recurrent state
    __half2 wz2, wh2;                          // prefetched WX for current step
    if (gate) {
        const __half* wrow = WX + (size_t)(c * T_ + 0) * NG_;   // t=0: forward, batch c
        wz2 = *(const __half2*)(wrow + j0);
        wh2 = *(const __half2*)(wrow + H_ + j0);
    }

    for (int t = 0; t < STEPS_; ++t) {
        uint64_t* buf = myb + (size_t)(t & 1) * 512;
        uint32_t tag = (uint32_t)t;

        if (tid < 64) {        // wave 0: poll all 512 tagged values
            uint64_t v[8];
#pragma unroll
            for (int k = 0; k < 8; ++k)
                v[k] = __hip_atomic_load(&buf[tid + 64 * k], __ATOMIC_RELAXED,
                                         __HIP_MEMORY_SCOPE_AGENT);
            while (true) {
                uint32_t bad = 0;
#pragma unroll
                for (int k = 0; k < 8; ++k) bad |= ((uint32_t)(v[k] >> 32)) ^ tag;
                if (bad == 0) break;
#pragma unroll
                for (int k = 0; k < 8; ++k)
                    if ((uint32_t)(v[k] >> 32) != tag)
                        v[k] = __hip_atomic_load(&buf[tid + 64 * k], __ATOMIC_RELAXED,
                                                 __HIP_MEMORY_SCOPE_AGENT);
            }
#pragma unroll
            for (int k = 0; k < 8; ++k) {
                int col = tid + 64 * k;
                h_s[(col >> 5) * 40 + (col & 31)] =
                    __float2half(__uint_as_float((uint32_t)v[k]));
            }
        }
        __syncthreads();   // h_s(t) staged

        // ---- 4-row x 32-chunk dot (64 B of h, reused x4) ----
        float a0 = 0.f, a1 = 0.f, a2 = 0.f, a3 = 0.f;
        const uint4* h4 = (const uint4*)(h_s + ck * 40);
#pragma unroll
        for (int q = 0; q < 4; ++q) {
            uint4 hv = h4[q];
            a0 = dot2f(ureg[0][4 * q + 0], hv.x, a0);
            a0 = dot2f(ureg[0][4 * q + 1], hv.y, a0);
            a0 = dot2f(ureg[0][4 * q + 2], hv.z, a0);
            a0 = dot2f(ureg[0][4 * q + 3], hv.w, a0);
            a1 = dot2f(ureg[1][4 * q + 0], hv.x, a1);
            a1 = dot2f(ureg[1][4 * q + 1], hv.y, a1);
            a1 = dot2f(ureg[1][4 * q + 2], hv.z, a1);
            a1 = dot2f(ureg[1][4 * q + 3], hv.w, a1);
            a2 = dot2f(ureg[2][4 * q + 0], hv.x, a2);
            a2 = dot2f(ureg[2][4 * q + 1], hv.y, a2);
            a2 = dot2f(ureg[2][4 * q + 2], hv.z, a2);
            a2 = dot2f(ureg[2][4 * q + 3], hv.w, a2);
            a3 = dot2f(ureg[3][4 * q + 0], hv.x, a3);
            a3 = dot2f(ureg[3][4 * q + 1], hv.y, a3);
            a3 = dot2f(ureg[3][4 * q + 2], hv.z, a3);
            a3 = dot2f(ureg[3][4 * q + 3], hv.w, a3);
        }
#pragma unroll
        for (int m = 1; m < 16; m <<= 1) {
            a0 += __shfl_xor(a0, m);
            a1 += __shfl_xor(a1, m);
            a2 += __shfl_xor(a2, m);
            a3 += __shfl_xor(a3, m);
        }

        // ---- gate lanes: compute + publish immediately (no barrier on path) ----
        if (gate) {
            float2 wz = __half22float2(wz2), wh = __half22float2(wh2);
            float z0 = 1.f / (1.f + __expf(-(wz.x + a0)));
            float z1 = 1.f / (1.f + __expf(-(wz.y + a1)));
            float hc0 = fmaxf(wh.x + a2, 0.f);
            float hc1 = fmaxf(wh.y + a3, 0.f);
            float hn0 = z0 * hold0 + (1.f - z0) * hc0;
            float hn1 = z1 * hold1 + (1.f - z1) * hc1;
            hold0 = hn0; hold1 = hn1;
            uint64_t* nb = myb + (size_t)((t + 1) & 1) * 512;
            uint64_t tagup = (uint64_t)(uint32_t)(t + 1) << 32;
            __hip_atomic_store(&nb[j0], tagup | (uint64_t)__float_as_uint(hn0),
                               __ATOMIC_RELAXED, __HIP_MEMORY_SCOPE_AGENT);
            __hip_atomic_store(&nb[j0 + 1], tagup | (uint64_t)__float_as_uint(hn1),
                               __ATOMIC_RELAXED, __HIP_MEMORY_SCOPE_AGENT);
            // out_pre store (off critical path)
            size_t off;
            if (t < T_) off = ((size_t)(c * T_ + t)) * NG_ + j0;
            else        off = ((size_t)((B_ - 1 - c) * T_ + (t - T_))) * NG_ + H_ + j0;
            *(__half2*)(out_pre + off) = __floats2half2_rn(hn0, hn1);
            // prefetch WX for step t+1 (latency hides behind next poll)
            int tn2 = (t + 1 < STEPS_) ? (t + 1) : t;
            int sb = (tn2 < T_) ? c : (B_ - 1 - c);
            int st = (tn2 < T_) ? tn2 : (tn2 - T_);
            const __half* wrow = WX + (size_t)(sb * T_ + st) * NG_;
            wz2 = *(const __half2*)(wrow + j0);
            wh2 = *(const __half2*)(wrow + H_ + j0);
        }
        __syncthreads();   // all h_s(t) reads done -> safe to stage t+1
    }
}

// ---------------------------------------------------------------------------
// Phase 3a: LayerNorm over last dim (1024), in place on f16 buffer
// ---------------------------------------------------------------------------
__global__ __launch_bounds__(256) void ln_kernel(__half* __restrict__ buf,
                                                 const float* __restrict__ g,
                                                 const float* __restrict__ b) {
    __shared__ float red[2][4];
    int row = blockIdx.x, tid = threadIdx.x;
    __half* p = buf + (size_t)row * NG_ + tid * 4;
    uint2 raw = *(const uint2*)p;
    __half2 h01 = *(__half2*)&raw.x, h23 = *(__half2*)&raw.y;
    float2 f01 = __half22float2(h01), f23 = __half22float2(h23);
    float s = f01.x + f01.y + f23.x + f23.y;
    float ss = fmaf(f01.x, f01.x, fmaf(f01.y, f01.y, fmaf(f23.x, f23.x, f23.y * f23.y)));
#pragma unroll
    for (int m = 32; m >= 1; m >>= 1) { s += __shfl_xor(s, m); ss += __shfl_xor(ss, m); }
    int w = tid >> 6;
    if ((tid & 63) == 0) { red[0][w] = s; red[1][w] = ss; }
    __syncthreads();
    float S = red[0][0] + red[0][1] + red[0][2] + red[0][3];
    float SS = red[1][0] + red[1][1] + red[1][2] + red[1][3];
    float mu = S * (1.f / NG_);
    float var = SS * (1.f / NG_) - mu * mu;
    float rstd = rsqrtf(var + 1e-5f);
    int d = tid * 4;
    float o0 = (f01.x - mu) * rstd * g[d + 0] + b[d + 0];
    float o1 = (f01.y - mu) * rstd * g[d + 1] + b[d + 1];
    float o2 = (f23.x - mu) * rstd * g[d + 2] + b[d + 2];
    float o3 = (f23.y - mu) * rstd * g[d + 3] + b[d + 3];
    __half2 a = __floats2half2_rn(o0, o1), c = __floats2half2_rn(o2, o3);
    uint2 out; out.x = *(uint32_t*)&a; out.y = *(uint32_t*)&c;
    *(uint2*)p = out;
}

// ---------------------------------------------------------------------------
// Phase 3b: projection GEMM: out[m,e] = tanh(LN[m,:] . pjW[e,:] + pjb[e]), fp32 out
// ---------------------------------------------------------------------------
__global__ __launch_bounds__(256) void gemm_proj(
    const __half* __restrict__ Ain, const float* __restrict__ pjW,
    const float* __restrict__ pjb, float* __restrict__ outp)
{
    __shared__ float As[16][132];
    __shared__ float Bs[16][144];
    int tid = threadIdx.x;
    int bm = blockIdx.x >> 3, bn = blockIdx.x & 7;
    int m0 = bm * 128, n0 = bn * 128;
    int tm = tid >> 4, tn = tid & 15;
    float acc[8][8] = {};

    for (int k0 = 0; k0 < 1024; k0 += 16) {
        {
            int row = tid >> 1, hb = (tid & 1) * 8;
            uint4 raw = *(const uint4*)(Ain + (size_t)(m0 + row) * NG_ + k0 + hb);
            const __half2* hp = (const __half2*)&raw;
#pragma unroll
            for (int q = 0; q < 4; ++q) {
                float2 f = __half22float2(hp[q]);
                As[hb + 2 * q][row] = f.x;
                As[hb + 2 * q + 1][row] = f.y;
            }
        }
#pragma unroll
        for (int i = 0; i < 2; ++i) {
            int f = tid * 2 + i;
            int row = f >> 2, c4 = (f & 3) * 4;
            float4 v = *(const float4*)(pjW + (size_t)(n0 + row) * 1024 + k0 + c4);
            int r = swz(row);
            Bs[c4 + 0][r] = v.x; Bs[c4 + 1][r] = v.y;
            Bs[c4 + 2][r] = v.z; Bs[c4 + 3][r] = v.w;
        }
        __syncthreads();
#pragma unroll
        for (int kk = 0; kk < 16; ++kk) {
            float a[8], b[8];
            *(float4*)&a[0] = *(const float4*)&As[kk][tm * 8];
            *(float4*)&a[4] = *(const float4*)&As[kk][tm * 8 + 4];
            *(float4*)&b[0] = *(const float4*)&Bs[kk][swz(tn * 8)];
            *(float4*)&b[4] = *(const float4*)&Bs[kk][swz(tn * 8) + 4];
#pragma unroll
            for (int i = 0; i < 8; ++i)
#pragma unroll
                for (int j = 0; j < 8; ++j)
                    acc[i][j] = fmaf(a[i], b[j], acc[i][j]);
        }
        __syncthreads();
    }

#pragma unroll
    for (int i = 0; i < 8; ++i) {
        size_t rowoff = (size_t)(m0 + tm * 8 + i) * NG_ + n0 + tn * 8;
#pragma unroll
        for (int j = 0; j < 8; ++j) {
            int n = n0 + tn * 8 + j;
            outp[rowoff + j] = tanhf(acc[i][j] + pjb[n]);
        }
    }
}

// ---------------------------------------------------------------------------
extern "C" void kernel_launch(void* const* d_in, const int* in_sizes, int n_in,
                              void* d_out, int out_size, void* d_ws, size_t ws_size,
                              hipStream_t stream) {
    const float* x    = (const float*)d_in[0];
    const int*   xlen = (const int*)  d_in[1];
    const float* Wz   = (const float*)d_in[2];
    const float* bz   = (const float*)d_in[3];
    const float* Wh   = (const float*)d_in[4];
    const float* bh   = (const float*)d_in[5];
    const float* U    = (const float*)d_in[6];
    const float* zg   = (const float*)d_in[7];
    const float* zb   = (const float*)d_in[8];
    const float* zm   = (const float*)d_in[9];
    const float* zv   = (const float*)d_in[10];
    const float* hg   = (const float*)d_in[11];
    const float* hb   = (const float*)d_in[12];
    const float* hm   = (const float*)d_in[13];
    const float* hv   = (const float*)d_in[14];
    const float* lng  = (const float*)d_in[15];
    const float* lnb  = (const float*)d_in[16];
    const float* pjW  = (const float*)d_in[17];
    const float* pjb  = (const float*)d_in[18];

    char* ws = (char*)d_ws;
    __half*   WX      = (__half*)(ws + WX_OFF);
    __half*   out_pre = (__half*)(ws + OUTPRE_OFF);
    uint64_t* htag    = (uint64_t*)(ws + HTAG_OFF);
    float* out = (float*)d_out;

    init_kernel<<<64, 256, 0, stream>>>(htag, xlen, out + (size_t)M1_ * NG_);
    gemm_gates<<<1000, 256, 0, stream>>>(x, Wz, Wh, bz, bh, zg, zb, zm, zv,
                                         hg, hb, hm, hv, WX);
    recur_kernel<<<128, 512, 0, stream>>>(WX, U, htag, out_pre);
    ln_kernel<<<M1_, 256, 0, stream>>>(out_pre, lng, lnb);
    gemm_proj<<<1000, 256, 0, stream>>>(out_pre, pjW, pjb, out);
}